// Round 5
// baseline (2285.335 us; speedup 1.0000x reference)
//
#include <hip/hip_runtime.h>
#include <math.h>

#define BB 4
#define NN 8192
#define DD 256
#define KK 512
#define NITERS 10

#define MT 128    // points per block in assign
#define KT 256    // clusters per k-chunk
#define DC 32     // d chunk staged in LDS

#define XS2 132   // padded LDS stride for xs[d][m]  (128 + 4)
#define CS2 260   // padded LDS stride for cs[d][k]  (256 + 4)
#define TAU 0.0625f   // top2 margin below which we re-rank in f64

#define NCH 128   // 64-point chunks per batch (NN/64)

// ---------------- init: centers0 = x[:, :K, :] ----------------
__global__ __launch_bounds__(256) void init_centers_k(const float* __restrict__ x,
                                                      float* __restrict__ centers) {
    int bk = blockIdx.x;
    int b  = bk >> 9;
    int k  = bk & 511;
    centers[(size_t)bk * DD + threadIdx.x] = x[((size_t)b * NN + k) * DD + threadIdx.x];
}

// ---------------- row sum of squares, numpy-pairwise order ----------------
__global__ __launch_bounds__(256) void rowsumsq_k(const float* __restrict__ rows,
                                                  float* __restrict__ out, int nrows) {
    int r = blockIdx.x * 256 + threadIdx.x;
    if (r >= nrows) return;
    const float* p = rows + (size_t)r * DD;
    float total = 0.f;
    #pragma unroll
    for (int h = 0; h < 2; ++h) {
        float a[8];
        #pragma unroll
        for (int j = 0; j < 8; ++j) a[j] = 0.f;
        for (int i = 0; i < 128; i += 8) {
            #pragma unroll
            for (int j = 0; j < 8; ++j) {
                float v  = p[h * 128 + i + j];
                float sq = __fmul_rn(v, v);
                a[j] = __fadd_rn(a[j], sq);
            }
        }
        float s = __fadd_rn(__fadd_rn(__fadd_rn(a[0], a[1]), __fadd_rn(a[2], a[3])),
                            __fadd_rn(__fadd_rn(a[4], a[5]), __fadd_rn(a[6], a[7])));
        total = __fadd_rn(total, s);
    }
    out[r] = total;
}

// ---------------- fused distance / top-2 argmin, flag marginal points ------
// 256 threads; tile M=128 x K=256; per-thread 8 pts x 16 clusters.
// x reads broadcast; c reads 4x contiguous-256B b128 (2-way, free);
// staging writes lane-stride-1 columns (2-way, free).
__global__ __launch_bounds__(256) void assign_k(
    const float* __restrict__ x, const float* __restrict__ centers,
    const float* __restrict__ x2g, const float* __restrict__ c2g,
    int* __restrict__ labels, int* __restrict__ flagcnt, int* __restrict__ flaglist)
{
    __shared__ float xs[DC][XS2];
    __shared__ float cs[DC][CS2];

    const int tid = threadIdx.x;
    const int tkk = tid & 15;
    const int tmm = tid >> 4;       // 0..15
    const int bx  = blockIdx.x;
    const int b   = bx >> 6;        // NN/MT = 64 blocks per batch
    const int m0  = (bx & 63) * MT;

    const float* xb = x       + (size_t)b * NN * DD;
    const float* cb = centers + (size_t)b * KK * DD;

    float x2m[8];
    #pragma unroll
    for (int i = 0; i < 8; ++i)
        x2m[i] = x2g[b * NN + m0 + (i >> 2) * 64 + tmm * 4 + (i & 3)];

    float rv1[8], rv2[8];
    int   rk1[8];
    #pragma unroll
    for (int i = 0; i < 8; ++i) { rv1[i] = __builtin_inff(); rv2[i] = __builtin_inff(); rk1[i] = 0x7fffffff; }

    const int xrow = tid >> 1;          // 0..127
    const int xg   = (tid & 1) * 4;     // granule base 0 or 4

    for (int kc = 0; kc < KK; kc += KT) {
        float acc[8][16];
        #pragma unroll
        for (int i = 0; i < 8; ++i)
            #pragma unroll
            for (int j = 0; j < 16; ++j) acc[i][j] = 0.f;

        for (int d0 = 0; d0 < DD; d0 += DC) {
            __syncthreads();
            // stage x tile (128 rows x 32 d), transposed: xs[d][m]
            #pragma unroll
            for (int q = 0; q < 4; ++q) {
                float4 v = *(const float4*)(xb + (size_t)(m0 + xrow) * DD + d0 + (xg + q) * 4);
                int dd = (xg + q) * 4;
                xs[dd + 0][xrow] = v.x; xs[dd + 1][xrow] = v.y;
                xs[dd + 2][xrow] = v.z; xs[dd + 3][xrow] = v.w;
            }
            // stage c tile (256 rows x 32 d), transposed: cs[d][k], 1 row/thread
            #pragma unroll
            for (int g = 0; g < 8; ++g) {
                float4 v = *(const float4*)(cb + (size_t)(kc + tid) * DD + d0 + g * 4);
                int dd = g * 4;
                cs[dd + 0][tid] = v.x; cs[dd + 1][tid] = v.y;
                cs[dd + 2][tid] = v.z; cs[dd + 3][tid] = v.w;
            }
            __syncthreads();
            #pragma unroll 2
            for (int d = 0; d < DC; ++d) {
                const float4 xa  = *(const float4*)&xs[d][tmm * 4];
                const float4 xbv = *(const float4*)&xs[d][64 + tmm * 4];
                float xf[8] = {xa.x, xa.y, xa.z, xa.w, xbv.x, xbv.y, xbv.z, xbv.w};
                float cf[16];
                #pragma unroll
                for (int q = 0; q < 4; ++q) {
                    const float4 cv = *(const float4*)&cs[d][q * 64 + tkk * 4];
                    cf[q * 4 + 0] = cv.x; cf[q * 4 + 1] = cv.y;
                    cf[q * 4 + 2] = cv.z; cf[q * 4 + 3] = cv.w;
                }
                #pragma unroll
                for (int i = 0; i < 8; ++i)
                    #pragma unroll
                    for (int j = 0; j < 16; ++j)
                        acc[i][j] += xf[i] * cf[j];
            }
        }

        // epilogue: candidates + top-2 argmin for this k-chunk
        float c2v[16];
        #pragma unroll
        for (int q = 0; q < 4; ++q)
            #pragma unroll
            for (int j = 0; j < 4; ++j)
                c2v[q * 4 + j] = c2g[b * KK + kc + q * 64 + tkk * 4 + j];

        #pragma unroll
        for (int i = 0; i < 8; ++i) {
            float v1 = __builtin_inff(), v2 = __builtin_inff();
            int   k1 = 0x7fffffff;
            #pragma unroll
            for (int q = 0; q < 4; ++q)
                #pragma unroll
                for (int j = 0; j < 4; ++j) {
                    int jj   = q * 4 + j;
                    int kidx = kc + q * 64 + tkk * 4 + j;   // ascending over (q,j)
                    float t    = __fmul_rn(2.0f, acc[i][jj]);
                    float cand = __fadd_rn(__fsub_rn(x2m[i], t), c2v[jj]);
                    if (cand < v1 || (cand == v1 && kidx < k1)) { v2 = v1; v1 = cand; k1 = kidx; }
                    else if (cand < v2) v2 = cand;
                }
            #pragma unroll
            for (int off = 1; off < 16; off <<= 1) {
                float ov1 = __shfl_xor(v1, off, 64);
                int   ok1 = __shfl_xor(k1, off, 64);
                float ov2 = __shfl_xor(v2, off, 64);
                if (ov1 < v1 || (ov1 == v1 && ok1 < k1)) { v2 = fminf(v1, ov2); v1 = ov1; k1 = ok1; }
                else { v2 = fminf(v2, ov1); }
            }
            if (v1 < rv1[i] || (v1 == rv1[i] && k1 < rk1[i])) {
                rv2[i] = fminf(rv1[i], v2); rv1[i] = v1; rk1[i] = k1;
            } else {
                rv2[i] = fminf(rv2[i], v1);
            }
        }
    }

    if (tkk == 0) {
        #pragma unroll
        for (int i = 0; i < 8; ++i) {
            int g = b * NN + m0 + (i >> 2) * 64 + tmm * 4 + (i & 3);
            labels[g] = rk1[i];
            if (rv2[i] - rv1[i] < TAU) {
                int pos = atomicAdd(flagcnt, 1);
                flaglist[pos] = g;
            }
        }
    }
}

// ---------------- exact (f64) re-rank of flagged points --------------------
__global__ __launch_bounds__(256) void refine_k(const float* __restrict__ x,
                                                const float* __restrict__ centers,
                                                const int* __restrict__ flagcnt,
                                                const int* __restrict__ flaglist,
                                                int* __restrict__ labels) {
    __shared__ float  xsr[DD];
    __shared__ double sv[256];
    __shared__ int    si[256];
    const int t = threadIdx.x;
    const int cnt = flagcnt[0];
    for (int idx = blockIdx.x; idx < cnt; idx += gridDim.x) {
        const int g = flaglist[idx];
        const int b = g >> 13;
        __syncthreads();
        xsr[t] = x[(size_t)g * DD + t];
        __syncthreads();
        const float* cbase = centers + (size_t)b * KK * DD;
        double bestv = 1e300; int bestk = 0x7fffffff;
        #pragma unroll
        for (int h = 0; h < 2; ++h) {
            int k = t + h * 256;
            const float* cr = cbase + (size_t)k * DD;
            double a0 = 0, a1 = 0, a2 = 0, a3 = 0;
            for (int d = 0; d < DD; d += 4) {
                double f0 = (double)xsr[d + 0] - (double)cr[d + 0];
                double f1 = (double)xsr[d + 1] - (double)cr[d + 1];
                double f2 = (double)xsr[d + 2] - (double)cr[d + 2];
                double f3 = (double)xsr[d + 3] - (double)cr[d + 3];
                a0 += f0 * f0; a1 += f1 * f1; a2 += f2 * f2; a3 += f3 * f3;
            }
            double dist = (a0 + a1) + (a2 + a3);
            if (dist < bestv || (dist == bestv && k < bestk)) { bestv = dist; bestk = k; }
        }
        sv[t] = bestv; si[t] = bestk;
        __syncthreads();
        for (int s = 128; s > 0; s >>= 1) {
            if (t < s) {
                if (sv[t + s] < sv[t] || (sv[t + s] == sv[t] && si[t + s] < si[t])) {
                    sv[t] = sv[t + s]; si[t] = si[t + s];
                }
            }
            __syncthreads();
        }
        if (t == 0) labels[g] = si[0];
    }
}

// ------- parallel stable counting sort: hist -> scan -> scatter ------------
__global__ __launch_bounds__(64) void chunk_hist_k(const int* __restrict__ labels,
                                                   int* __restrict__ chunkhist) {
    __shared__ int h[KK];
    const int bc = blockIdx.x;        // b*NCH + c
    const int b  = bc >> 7;
    const int c  = bc & (NCH - 1);
    const int t  = threadIdx.x;
    for (int k = t; k < KK; k += 64) h[k] = 0;
    __syncthreads();
    int l = labels[b * NN + c * 64 + t];
    atomicAdd(&h[l], 1);
    __syncthreads();
    int* ch = chunkhist + (size_t)bc * KK;
    for (int k = t; k < KK; k += 64) ch[k] = h[k];
}

__global__ __launch_bounds__(512) void scan_k(int* __restrict__ chunkhist,
                                              int* __restrict__ counts,
                                              int* __restrict__ offsets) {
    __shared__ int s[KK];
    const int b = blockIdx.x;
    const int k = threadIdx.x;
    int* ch = chunkhist + (size_t)b * NCH * KK;
    int run = 0;
    for (int c = 0; c < NCH; ++c) {
        int v = ch[(size_t)c * KK + k];
        ch[(size_t)c * KK + k] = run;
        run += v;
    }
    counts[b * KK + k] = run;
    s[k] = run;
    __syncthreads();
    for (int off = 1; off < KK; off <<= 1) {
        int v = (k >= off) ? s[k - off] : 0;
        __syncthreads();
        s[k] += v;
        __syncthreads();
    }
    offsets[b * KK + k] = s[k] - run;   // exclusive
}

__global__ __launch_bounds__(64) void scatter_k(const int* __restrict__ labels,
                                                const int* __restrict__ chunkhist,
                                                const int* __restrict__ offsets,
                                                int* __restrict__ idxlist) {
    const int bc = blockIdx.x;
    const int b  = bc >> 7;
    const int c  = bc & (NCH - 1);
    const int t  = threadIdx.x;
    const int n  = c * 64 + t;
    const int l  = labels[b * NN + n];
    int rank = 0;
    for (int j = 0; j < 64; ++j) {
        int lj = __shfl(l, j, 64);
        rank += (lj == l && j < t) ? 1 : 0;
    }
    int base = offsets[b * KK + l] + chunkhist[(size_t)bc * KK + l];
    idxlist[b * NN + base + rank] = n;
}

// ------- centers update: member-parallel (16 waves), deterministic ---------
__global__ __launch_bounds__(1024) void centers_update_k(const float* __restrict__ x,
                                                         float* __restrict__ centers,
                                                         const int* __restrict__ counts,
                                                         const int* __restrict__ offsets,
                                                         const int* __restrict__ idxlist,
                                                         int* __restrict__ flagcnt) {
    __shared__ float part[16][DD];
    const int bk   = blockIdx.x;
    const int b    = bk >> 9;
    const int tid  = threadIdx.x;
    const int w    = tid >> 6;        // 0..15
    const int lane = tid & 63;
    if (bk == 0 && tid == 0) flagcnt[0] = 0;   // reset for next assign pass
    const int cnt = counts[bk];
    if (cnt == 0) return;             // uniform across block
    const int* il = idxlist + b * NN + offsets[bk];
    const float* xb = x + (size_t)b * NN * DD;
    float4 acc = {0.f, 0.f, 0.f, 0.f};
    for (int j = w; j < cnt; j += 16) {
        int n = il[j];
        float4 v = *(const float4*)(xb + (size_t)n * DD + lane * 4);
        acc.x = __fadd_rn(acc.x, v.x);
        acc.y = __fadd_rn(acc.y, v.y);
        acc.z = __fadd_rn(acc.z, v.z);
        acc.w = __fadd_rn(acc.w, v.w);
    }
    *(float4*)&part[w][lane * 4] = acc;
    __syncthreads();
    if (tid < DD) {
        float s = 0.f;
        #pragma unroll
        for (int w2 = 0; w2 < 16; ++w2) s = __fadd_rn(s, part[w2][tid]);
        centers[(size_t)bk * DD + tid] = s / (float)cnt;
    }
}

__global__ __launch_bounds__(256) void labels_to_float_k(const int* __restrict__ labels,
                                                         float* __restrict__ out) {
    int i = blockIdx.x * 256 + threadIdx.x;
    out[i] = (float)labels[i];
}

__global__ __launch_bounds__(256) void copy_centers_k(const float* __restrict__ centers,
                                                      float* __restrict__ out) {
    size_t i = (size_t)blockIdx.x * 256 + threadIdx.x;
    out[i] = centers[i];
}

extern "C" void kernel_launch(void* const* d_in, const int* in_sizes, int n_in,
                              void* d_out, int out_size, void* d_ws, size_t ws_size,
                              hipStream_t stream) {
    const float* x = (const float*)d_in[0];
    float* out = (float*)d_out;
    float* ws  = (float*)d_ws;

    // ws layout
    float* centers  = ws;                                   // BB*KK*DD
    float* c2       = centers + (size_t)BB * KK * DD;       // BB*KK
    float* x2       = c2 + BB * KK;                         // BB*NN
    int*   labels   = (int*)(x2 + BB * NN);                 // BB*NN
    int*   flagcnt  = labels + BB * NN;                     // 64
    int*   flaglist = flagcnt + 64;                         // BB*NN
    int*   counts   = flaglist + BB * NN;                   // BB*KK
    int*   offsets  = counts + BB * KK;                     // BB*KK
    int*   idxlist  = offsets + BB * KK;                    // BB*NN
    int*   chunkhist= idxlist + BB * NN;                    // BB*NCH*KK

    hipMemsetAsync(flagcnt, 0, 64 * sizeof(int), stream);

    init_centers_k<<<BB * KK, 256, 0, stream>>>(x, centers);
    rowsumsq_k<<<(BB * NN + 255) / 256, 256, 0, stream>>>(x, x2, BB * NN);

    for (int it = 0; it < NITERS; ++it) {
        rowsumsq_k<<<(BB * KK + 255) / 256, 256, 0, stream>>>(centers, c2, BB * KK);
        assign_k<<<BB * (NN / MT), 256, 0, stream>>>(x, centers, x2, c2,
                                                     labels, flagcnt, flaglist);
        refine_k<<<64, 256, 0, stream>>>(x, centers, flagcnt, flaglist, labels);
        chunk_hist_k<<<BB * NCH, 64, 0, stream>>>(labels, chunkhist);
        scan_k<<<BB, 512, 0, stream>>>(chunkhist, counts, offsets);
        scatter_k<<<BB * NCH, 64, 0, stream>>>(labels, chunkhist, offsets, idxlist);
        centers_update_k<<<BB * KK, 1024, 0, stream>>>(x, centers, counts, offsets,
                                                       idxlist, flagcnt);
    }

    rowsumsq_k<<<(BB * KK + 255) / 256, 256, 0, stream>>>(centers, c2, BB * KK);
    assign_k<<<BB * (NN / MT), 256, 0, stream>>>(x, centers, x2, c2,
                                                 labels, flagcnt, flaglist);
    refine_k<<<64, 256, 0, stream>>>(x, centers, flagcnt, flaglist, labels);

    labels_to_float_k<<<BB * NN / 256, 256, 0, stream>>>(labels, out);
    copy_centers_k<<<BB * KK * DD / 256, 256, 0, stream>>>(centers, out + BB * NN);
}

// Round 6
// 2135.994 us; speedup vs baseline: 1.0699x; 1.0699x over previous
//
#include <hip/hip_runtime.h>
#include <math.h>

#define BB 4
#define NN 8192
#define DD 256
#define KK 512
#define NITERS 10

#define MT 64     // points per block in assign
#define KT 256    // clusters per k-chunk
#define DC 32     // d chunk staged in LDS

#define XSTR 68   // padded LDS stride for xs[d][m]  (64 + 4)
#define CSTR 260  // padded LDS stride for cs[d][k]  (256 + 4)
#define TAU 0.0625f   // top2 margin below which we re-rank in f64

#define NCH 128   // 64-point chunks per batch (NN/64)

// ---------------- init: centers0 = x[:, :K, :] ----------------
__global__ __launch_bounds__(256) void init_centers_k(const float* __restrict__ x,
                                                      float* __restrict__ centers) {
    int bk = blockIdx.x;
    int b  = bk >> 9;
    int k  = bk & 511;
    centers[(size_t)bk * DD + threadIdx.x] = x[((size_t)b * NN + k) * DD + threadIdx.x];
}

// ---------------- row sum of squares, numpy-pairwise order ----------------
__global__ __launch_bounds__(256) void rowsumsq_k(const float* __restrict__ rows,
                                                  float* __restrict__ out, int nrows) {
    int r = blockIdx.x * 256 + threadIdx.x;
    if (r >= nrows) return;
    const float* p = rows + (size_t)r * DD;
    float total = 0.f;
    #pragma unroll
    for (int h = 0; h < 2; ++h) {
        float a[8];
        #pragma unroll
        for (int j = 0; j < 8; ++j) a[j] = 0.f;
        for (int i = 0; i < 128; i += 8) {
            #pragma unroll
            for (int j = 0; j < 8; ++j) {
                float v  = p[h * 128 + i + j];
                float sq = __fmul_rn(v, v);
                a[j] = __fadd_rn(a[j], sq);
            }
        }
        float s = __fadd_rn(__fadd_rn(__fadd_rn(a[0], a[1]), __fadd_rn(a[2], a[3])),
                            __fadd_rn(__fadd_rn(a[4], a[5]), __fadd_rn(a[6], a[7])));
        total = __fadd_rn(total, s);
    }
    out[r] = total;
}

// ---------------- fused distance / top-2 argmin, flag marginal points ------
// 256 threads (4 waves); tile M=64 x K=256; per-thread 4 pts x 16 clusters.
// grid 512 blocks = 2 blocks/CU = 2 waves/SIMD (latency hiding restored).
__global__ __launch_bounds__(256) void assign_k(
    const float* __restrict__ x, const float* __restrict__ centers,
    const float* __restrict__ x2g, const float* __restrict__ c2g,
    int* __restrict__ labels, int* __restrict__ flagcnt, int* __restrict__ flaglist)
{
    __shared__ float xs[DC][XSTR];
    __shared__ float cs[DC][CSTR];

    const int tid = threadIdx.x;
    const int tkk = tid & 15;
    const int tmm = tid >> 4;       // 0..15
    const int bx  = blockIdx.x;
    const int b   = bx >> 7;        // NN/MT = 128 blocks per batch
    const int m0  = (bx & 127) * MT;

    const float* xb = x       + (size_t)b * NN * DD;
    const float* cb = centers + (size_t)b * KK * DD;

    float x2m[4];
    #pragma unroll
    for (int i = 0; i < 4; ++i) x2m[i] = x2g[b * NN + m0 + tmm * 4 + i];

    float rv1[4], rv2[4];
    int   rk1[4];
    #pragma unroll
    for (int i = 0; i < 4; ++i) { rv1[i] = __builtin_inff(); rv2[i] = __builtin_inff(); rk1[i] = 0x7fffffff; }

    const int xrow = tid & 63;      // lane-major: stride-1 LDS writes, free
    const int xh   = (tid >> 6) * 2;   // granule pair base (0,2,4,6)

    for (int kc = 0; kc < KK; kc += KT) {
        float acc[4][16];
        #pragma unroll
        for (int i = 0; i < 4; ++i)
            #pragma unroll
            for (int j = 0; j < 16; ++j) acc[i][j] = 0.f;

        for (int d0 = 0; d0 < DD; d0 += DC) {
            __syncthreads();
            // stage x tile (64 rows x 32 d), transposed: xs[d][m]
            #pragma unroll
            for (int p = 0; p < 2; ++p) {
                int g  = xh + p;                 // granule 0..7
                float4 v = *(const float4*)(xb + (size_t)(m0 + xrow) * DD + d0 + g * 4);
                int dd = g * 4;
                xs[dd + 0][xrow] = v.x; xs[dd + 1][xrow] = v.y;
                xs[dd + 2][xrow] = v.z; xs[dd + 3][xrow] = v.w;
            }
            // stage c tile (256 rows x 32 d), transposed: cs[d][k], 1 row/thread
            #pragma unroll
            for (int g = 0; g < 8; ++g) {
                float4 v = *(const float4*)(cb + (size_t)(kc + tid) * DD + d0 + g * 4);
                int dd = g * 4;
                cs[dd + 0][tid] = v.x; cs[dd + 1][tid] = v.y;
                cs[dd + 2][tid] = v.z; cs[dd + 3][tid] = v.w;
            }
            __syncthreads();
            #pragma unroll 2
            for (int d = 0; d < DC; ++d) {
                const float4 xv = *(const float4*)&xs[d][tmm * 4];
                float xf[4] = {xv.x, xv.y, xv.z, xv.w};
                float cf[16];
                #pragma unroll
                for (int q = 0; q < 4; ++q) {
                    const float4 cv = *(const float4*)&cs[d][q * 64 + tkk * 4];
                    cf[q * 4 + 0] = cv.x; cf[q * 4 + 1] = cv.y;
                    cf[q * 4 + 2] = cv.z; cf[q * 4 + 3] = cv.w;
                }
                #pragma unroll
                for (int i = 0; i < 4; ++i)
                    #pragma unroll
                    for (int j = 0; j < 16; ++j)
                        acc[i][j] += xf[i] * cf[j];
            }
        }

        // epilogue: candidates + top-2 argmin for this k-chunk
        float c2v[16];
        #pragma unroll
        for (int q = 0; q < 4; ++q)
            #pragma unroll
            for (int j = 0; j < 4; ++j)
                c2v[q * 4 + j] = c2g[b * KK + kc + q * 64 + tkk * 4 + j];

        #pragma unroll
        for (int i = 0; i < 4; ++i) {
            float v1 = __builtin_inff(), v2 = __builtin_inff();
            int   k1 = 0x7fffffff;
            #pragma unroll
            for (int q = 0; q < 4; ++q)
                #pragma unroll
                for (int j = 0; j < 4; ++j) {
                    int jj   = q * 4 + j;
                    int kidx = kc + q * 64 + tkk * 4 + j;   // ascending over (q,j)
                    float t    = __fmul_rn(2.0f, acc[i][jj]);
                    float cand = __fadd_rn(__fsub_rn(x2m[i], t), c2v[jj]);
                    if (cand < v1 || (cand == v1 && kidx < k1)) { v2 = v1; v1 = cand; k1 = kidx; }
                    else if (cand < v2) v2 = cand;
                }
            #pragma unroll
            for (int off = 1; off < 16; off <<= 1) {
                float ov1 = __shfl_xor(v1, off, 64);
                int   ok1 = __shfl_xor(k1, off, 64);
                float ov2 = __shfl_xor(v2, off, 64);
                if (ov1 < v1 || (ov1 == v1 && ok1 < k1)) { v2 = fminf(v1, ov2); v1 = ov1; k1 = ok1; }
                else { v2 = fminf(v2, ov1); }
            }
            if (v1 < rv1[i] || (v1 == rv1[i] && k1 < rk1[i])) {
                rv2[i] = fminf(rv1[i], v2); rv1[i] = v1; rk1[i] = k1;
            } else {
                rv2[i] = fminf(rv2[i], v1);
            }
        }
    }

    if (tkk == 0) {
        #pragma unroll
        for (int i = 0; i < 4; ++i) {
            int g = b * NN + m0 + tmm * 4 + i;
            labels[g] = rk1[i];
            if (rv2[i] - rv1[i] < TAU) {
                int pos = atomicAdd(flagcnt, 1);
                flaglist[pos] = g;
            }
        }
    }
}

// ---------------- exact (f64) re-rank of flagged points --------------------
__global__ __launch_bounds__(256) void refine_k(const float* __restrict__ x,
                                                const float* __restrict__ centers,
                                                const int* __restrict__ flagcnt,
                                                const int* __restrict__ flaglist,
                                                int* __restrict__ labels) {
    __shared__ float  xsr[DD];
    __shared__ double sv[256];
    __shared__ int    si[256];
    const int t = threadIdx.x;
    const int cnt = flagcnt[0];
    for (int idx = blockIdx.x; idx < cnt; idx += gridDim.x) {
        const int g = flaglist[idx];
        const int b = g >> 13;
        __syncthreads();
        xsr[t] = x[(size_t)g * DD + t];
        __syncthreads();
        const float* cbase = centers + (size_t)b * KK * DD;
        double bestv = 1e300; int bestk = 0x7fffffff;
        #pragma unroll
        for (int h = 0; h < 2; ++h) {
            int k = t + h * 256;
            const float* cr = cbase + (size_t)k * DD;
            double a0 = 0, a1 = 0, a2 = 0, a3 = 0;
            for (int d = 0; d < DD; d += 4) {
                double f0 = (double)xsr[d + 0] - (double)cr[d + 0];
                double f1 = (double)xsr[d + 1] - (double)cr[d + 1];
                double f2 = (double)xsr[d + 2] - (double)cr[d + 2];
                double f3 = (double)xsr[d + 3] - (double)cr[d + 3];
                a0 += f0 * f0; a1 += f1 * f1; a2 += f2 * f2; a3 += f3 * f3;
            }
            double dist = (a0 + a1) + (a2 + a3);
            if (dist < bestv || (dist == bestv && k < bestk)) { bestv = dist; bestk = k; }
        }
        sv[t] = bestv; si[t] = bestk;
        __syncthreads();
        for (int s = 128; s > 0; s >>= 1) {
            if (t < s) {
                if (sv[t + s] < sv[t] || (sv[t + s] == sv[t] && si[t + s] < si[t])) {
                    sv[t] = sv[t + s]; si[t] = si[t + s];
                }
            }
            __syncthreads();
        }
        if (t == 0) labels[g] = si[0];
    }
}

// ------- parallel stable counting sort: hist -> scan -> scatter ------------
__global__ __launch_bounds__(64) void chunk_hist_k(const int* __restrict__ labels,
                                                   int* __restrict__ chunkhist) {
    __shared__ int h[KK];
    const int bc = blockIdx.x;        // b*NCH + c
    const int b  = bc >> 7;
    const int c  = bc & (NCH - 1);
    const int t  = threadIdx.x;
    for (int k = t; k < KK; k += 64) h[k] = 0;
    __syncthreads();
    int l = labels[b * NN + c * 64 + t];
    atomicAdd(&h[l], 1);
    __syncthreads();
    int* ch = chunkhist + (size_t)bc * KK;
    for (int k = t; k < KK; k += 64) ch[k] = h[k];
}

__global__ __launch_bounds__(512) void scan_k(int* __restrict__ chunkhist,
                                              int* __restrict__ counts,
                                              int* __restrict__ offsets) {
    __shared__ int s[KK];
    const int b = blockIdx.x;
    const int k = threadIdx.x;
    int* ch = chunkhist + (size_t)b * NCH * KK;
    int run = 0;
    for (int c = 0; c < NCH; ++c) {
        int v = ch[(size_t)c * KK + k];
        ch[(size_t)c * KK + k] = run;
        run += v;
    }
    counts[b * KK + k] = run;
    s[k] = run;
    __syncthreads();
    for (int off = 1; off < KK; off <<= 1) {
        int v = (k >= off) ? s[k - off] : 0;
        __syncthreads();
        s[k] += v;
        __syncthreads();
    }
    offsets[b * KK + k] = s[k] - run;   // exclusive
}

__global__ __launch_bounds__(64) void scatter_k(const int* __restrict__ labels,
                                                const int* __restrict__ chunkhist,
                                                const int* __restrict__ offsets,
                                                int* __restrict__ idxlist) {
    const int bc = blockIdx.x;
    const int b  = bc >> 7;
    const int c  = bc & (NCH - 1);
    const int t  = threadIdx.x;
    const int n  = c * 64 + t;
    const int l  = labels[b * NN + n];
    int rank = 0;
    for (int j = 0; j < 64; ++j) {
        int lj = __shfl(l, j, 64);
        rank += (lj == l && j < t) ? 1 : 0;
    }
    int base = offsets[b * KK + l] + chunkhist[(size_t)bc * KK + l];
    idxlist[b * NN + base + rank] = n;
}

// ------- centers update: member-parallel (16 waves), deterministic ---------
__global__ __launch_bounds__(1024) void centers_update_k(const float* __restrict__ x,
                                                         float* __restrict__ centers,
                                                         const int* __restrict__ counts,
                                                         const int* __restrict__ offsets,
                                                         const int* __restrict__ idxlist,
                                                         int* __restrict__ flagcnt) {
    __shared__ float part[16][DD];
    const int bk   = blockIdx.x;
    const int b    = bk >> 9;
    const int tid  = threadIdx.x;
    const int w    = tid >> 6;        // 0..15
    const int lane = tid & 63;
    if (bk == 0 && tid == 0) flagcnt[0] = 0;   // reset for next assign pass
    const int cnt = counts[bk];
    if (cnt == 0) return;             // uniform across block
    const int* il = idxlist + b * NN + offsets[bk];
    const float* xb = x + (size_t)b * NN * DD;
    float4 acc = {0.f, 0.f, 0.f, 0.f};
    for (int j = w; j < cnt; j += 16) {
        int n = il[j];
        float4 v = *(const float4*)(xb + (size_t)n * DD + lane * 4);
        acc.x = __fadd_rn(acc.x, v.x);
        acc.y = __fadd_rn(acc.y, v.y);
        acc.z = __fadd_rn(acc.z, v.z);
        acc.w = __fadd_rn(acc.w, v.w);
    }
    *(float4*)&part[w][lane * 4] = acc;
    __syncthreads();
    if (tid < DD) {
        float s = 0.f;
        #pragma unroll
        for (int w2 = 0; w2 < 16; ++w2) s = __fadd_rn(s, part[w2][tid]);
        centers[(size_t)bk * DD + tid] = s / (float)cnt;
    }
}

__global__ __launch_bounds__(256) void labels_to_float_k(const int* __restrict__ labels,
                                                         float* __restrict__ out) {
    int i = blockIdx.x * 256 + threadIdx.x;
    out[i] = (float)labels[i];
}

__global__ __launch_bounds__(256) void copy_centers_k(const float* __restrict__ centers,
                                                      float* __restrict__ out) {
    size_t i = (size_t)blockIdx.x * 256 + threadIdx.x;
    out[i] = centers[i];
}

extern "C" void kernel_launch(void* const* d_in, const int* in_sizes, int n_in,
                              void* d_out, int out_size, void* d_ws, size_t ws_size,
                              hipStream_t stream) {
    const float* x = (const float*)d_in[0];
    float* out = (float*)d_out;
    float* ws  = (float*)d_ws;

    // ws layout
    float* centers  = ws;                                   // BB*KK*DD
    float* c2       = centers + (size_t)BB * KK * DD;       // BB*KK
    float* x2       = c2 + BB * KK;                         // BB*NN
    int*   labels   = (int*)(x2 + BB * NN);                 // BB*NN
    int*   flagcnt  = labels + BB * NN;                     // 64
    int*   flaglist = flagcnt + 64;                         // BB*NN
    int*   counts   = flaglist + BB * NN;                   // BB*KK
    int*   offsets  = counts + BB * KK;                     // BB*KK
    int*   idxlist  = offsets + BB * KK;                    // BB*NN
    int*   chunkhist= idxlist + BB * NN;                    // BB*NCH*KK

    hipMemsetAsync(flagcnt, 0, 64 * sizeof(int), stream);

    init_centers_k<<<BB * KK, 256, 0, stream>>>(x, centers);
    rowsumsq_k<<<(BB * NN + 255) / 256, 256, 0, stream>>>(x, x2, BB * NN);

    for (int it = 0; it < NITERS; ++it) {
        rowsumsq_k<<<(BB * KK + 255) / 256, 256, 0, stream>>>(centers, c2, BB * KK);
        assign_k<<<BB * (NN / MT), 256, 0, stream>>>(x, centers, x2, c2,
                                                     labels, flagcnt, flaglist);
        refine_k<<<64, 256, 0, stream>>>(x, centers, flagcnt, flaglist, labels);
        chunk_hist_k<<<BB * NCH, 64, 0, stream>>>(labels, chunkhist);
        scan_k<<<BB, 512, 0, stream>>>(chunkhist, counts, offsets);
        scatter_k<<<BB * NCH, 64, 0, stream>>>(labels, chunkhist, offsets, idxlist);
        centers_update_k<<<BB * KK, 1024, 0, stream>>>(x, centers, counts, offsets,
                                                       idxlist, flagcnt);
    }

    rowsumsq_k<<<(BB * KK + 255) / 256, 256, 0, stream>>>(centers, c2, BB * KK);
    assign_k<<<BB * (NN / MT), 256, 0, stream>>>(x, centers, x2, c2,
                                                 labels, flagcnt, flaglist);
    refine_k<<<64, 256, 0, stream>>>(x, centers, flagcnt, flaglist, labels);

    labels_to_float_k<<<BB * NN / 256, 256, 0, stream>>>(labels, out);
    copy_centers_k<<<BB * KK * DD / 256, 256, 0, stream>>>(centers, out + BB * NN);
}

// Round 7
// 1270.142 us; speedup vs baseline: 1.7993x; 1.6817x over previous
//
#include <hip/hip_runtime.h>
#include <math.h>

#define BB 4
#define NN 8192
#define DD 256
#define KK 512
#define NITERS 10

#define TAU 0.5f      // f16-dot margin below which we re-rank in f64
#define NCH 128       // 64-point chunks per batch (NN/64)
#define XLS 264       // xl row stride in f16 (256 + 8) — breaks A-read bank conflict

typedef _Float16 f16;
typedef f16   f16x8 __attribute__((ext_vector_type(8)));
typedef float f32x4 __attribute__((ext_vector_type(4)));

// ---------------- init: centers0 = x[:, :K, :]  (f32 + f16 mirror) --------
__global__ __launch_bounds__(256) void init_centers_k(const float* __restrict__ x,
                                                      float* __restrict__ centers,
                                                      f16* __restrict__ ch16) {
    int bk = blockIdx.x;
    int b  = bk >> 9;
    int k  = bk & 511;
    float v = x[((size_t)b * NN + k) * DD + threadIdx.x];
    centers[(size_t)bk * DD + threadIdx.x] = v;
    ch16[(size_t)bk * DD + threadIdx.x] = (f16)v;
}

// ---------------- row sum of squares, numpy-pairwise order ----------------
__global__ __launch_bounds__(256) void rowsumsq_k(const float* __restrict__ rows,
                                                  float* __restrict__ out, int nrows) {
    int r = blockIdx.x * 256 + threadIdx.x;
    if (r >= nrows) return;
    const float* p = rows + (size_t)r * DD;
    float total = 0.f;
    #pragma unroll
    for (int h = 0; h < 2; ++h) {
        float a[8];
        #pragma unroll
        for (int j = 0; j < 8; ++j) a[j] = 0.f;
        for (int i = 0; i < 128; i += 8) {
            #pragma unroll
            for (int j = 0; j < 8; ++j) {
                float v  = p[h * 128 + i + j];
                float sq = __fmul_rn(v, v);
                a[j] = __fadd_rn(a[j], sq);
            }
        }
        float s = __fadd_rn(__fadd_rn(__fadd_rn(a[0], a[1]), __fadd_rn(a[2], a[3])),
                            __fadd_rn(__fadd_rn(a[4], a[5]), __fadd_rn(a[6], a[7])));
        total = __fadd_rn(total, s);
    }
    out[r] = total;
}

// ---------------- MFMA distance / top-2 argmin, flag marginal points ------
// Block: 64 points x ALL 512 clusters. 4 waves, each 64m x 128k.
// A = x (f16, converted in-kernel, staged once); B = c^T (f16 mirror).
// acc[mi][ki] f32x4: point row = mi*16 + (lane>>4)*4 + r, cluster col =
// wid*128 + ki*16 + (lane&15). Top-2 via in-thread scan + 4-step butterfly
// over low-nibble lanes + cross-wave LDS merge (ascending-k tie-break).
__global__ __launch_bounds__(256, 2) void assign_k(
    const float* __restrict__ x, const f16* __restrict__ ch,
    const float* __restrict__ x2g, const float* __restrict__ c2g,
    int* __restrict__ labels, int* __restrict__ flagcnt, int* __restrict__ flaglist)
{
    __shared__ f16 xl[64 * XLS];
    __shared__ f16 cl[512 * 32];
    __shared__ float rv1s[4][64];
    __shared__ float rv2s[4][64];
    __shared__ int   rk1s[4][64];

    const int tid  = threadIdx.x;
    const int wid  = tid >> 6;
    const int lane = tid & 63;
    const int l15  = lane & 15;
    const int lg   = lane >> 4;          // 0..3
    const int b    = blockIdx.x >> 7;    // 128 blocks per batch
    const int m0   = (blockIdx.x & 127) * 64;

    const float* xb = x  + (size_t)(b * NN + m0) * DD;
    const f16*   cb = ch + (size_t)b * KK * DD;

    // stage x tile (64 x 256), f32->f16, once
    #pragma unroll
    for (int i = 0; i < 8; ++i) {
        int seg = tid + i * 256;          // 0..2047
        int row = seg >> 5, s = seg & 31;
        const float* p = xb + row * DD + s * 8;
        float4 a  = *(const float4*)p;
        float4 bq = *(const float4*)(p + 4);
        f16x8 hv;
        hv[0] = (f16)a.x;  hv[1] = (f16)a.y;  hv[2] = (f16)a.z;  hv[3] = (f16)a.w;
        hv[4] = (f16)bq.x; hv[5] = (f16)bq.y; hv[6] = (f16)bq.z; hv[7] = (f16)bq.w;
        *(f16x8*)&xl[row * XLS + s * 8] = hv;
    }

    f32x4 acc[4][8];
    #pragma unroll
    for (int mi = 0; mi < 4; ++mi)
        #pragma unroll
        for (int ki = 0; ki < 8; ++ki)
            acc[mi][ki] = (f32x4){0.f, 0.f, 0.f, 0.f};

    for (int d0 = 0; d0 < DD; d0 += 32) {
        __syncthreads();                  // prev reads done (also covers x-stage)
        // stage c chunk (512 k x 32 d) from f16 mirror
        #pragma unroll
        for (int i = 0; i < 8; ++i) {
            int seg = tid + i * 256;
            int kr = seg >> 2, s = seg & 3;
            float4 v = *(const float4*)(cb + (size_t)kr * DD + d0 + s * 8);  // 8 f16
            *(float4*)&cl[kr * 32 + s * 8] = v;
        }
        __syncthreads();

        f16x8 af[4];
        #pragma unroll
        for (int mi = 0; mi < 4; ++mi)
            af[mi] = *(const f16x8*)&xl[(mi * 16 + l15) * XLS + d0 + lg * 8];
        #pragma unroll
        for (int ki = 0; ki < 8; ++ki) {
            f16x8 bf = *(const f16x8*)&cl[(wid * 128 + ki * 16 + l15) * 32 + lg * 8];
            #pragma unroll
            for (int mi = 0; mi < 4; ++mi)
                acc[mi][ki] = __builtin_amdgcn_mfma_f32_16x16x32_f16(af[mi], bf,
                                                                     acc[mi][ki], 0, 0, 0);
        }
    }

    // epilogue: candidates + top-2
    float c2v[8];
    #pragma unroll
    for (int ki = 0; ki < 8; ++ki)
        c2v[ki] = c2g[b * KK + wid * 128 + ki * 16 + l15];

    #pragma unroll
    for (int mi = 0; mi < 4; ++mi) {
        #pragma unroll
        for (int r = 0; r < 4; ++r) {
            int p = mi * 16 + lg * 4 + r;
            float x2p = x2g[b * NN + m0 + p];
            float v1 = __builtin_inff(), v2 = __builtin_inff();
            int   k1 = 0x7fffffff;
            #pragma unroll
            for (int ki = 0; ki < 8; ++ki) {
                float s    = acc[mi][ki][r];
                float cand = __fadd_rn(__fsub_rn(x2p, __fmul_rn(2.0f, s)), c2v[ki]);
                int   kidx = wid * 128 + ki * 16 + l15;
                if (cand < v1 || (cand == v1 && kidx < k1)) { v2 = v1; v1 = cand; k1 = kidx; }
                else if (cand < v2) v2 = cand;
            }
            #pragma unroll
            for (int off = 1; off < 16; off <<= 1) {
                float ov1 = __shfl_xor(v1, off, 64);
                int   ok1 = __shfl_xor(k1, off, 64);
                float ov2 = __shfl_xor(v2, off, 64);
                if (ov1 < v1 || (ov1 == v1 && ok1 < k1)) { v2 = fminf(v1, ov2); v1 = ov1; k1 = ok1; }
                else v2 = fminf(v2, ov1);
            }
            if (l15 == 0) { rv1s[wid][p] = v1; rv2s[wid][p] = v2; rk1s[wid][p] = k1; }
        }
    }
    __syncthreads();
    if (tid < 64) {
        float v1 = rv1s[0][tid], v2 = rv2s[0][tid];
        int   k1 = rk1s[0][tid];
        #pragma unroll
        for (int w = 1; w < 4; ++w) {
            float ov1 = rv1s[w][tid], ov2 = rv2s[w][tid];
            int   ok1 = rk1s[w][tid];
            if (ov1 < v1 || (ov1 == v1 && ok1 < k1)) { v2 = fminf(v1, ov2); v1 = ov1; k1 = ok1; }
            else v2 = fminf(v2, ov1);
        }
        int g = b * NN + m0 + tid;
        labels[g] = k1;
        if (v2 - v1 < TAU) {
            int pos = atomicAdd(flagcnt, 1);
            flaglist[pos] = g;
        }
    }
}

// ---------------- exact (f64) re-rank of flagged points --------------------
__global__ __launch_bounds__(256) void refine_k(const float* __restrict__ x,
                                                const float* __restrict__ centers,
                                                const int* __restrict__ flagcnt,
                                                const int* __restrict__ flaglist,
                                                int* __restrict__ labels) {
    __shared__ float  xsr[DD];
    __shared__ double sv[256];
    __shared__ int    si[256];
    const int t = threadIdx.x;
    const int cnt = flagcnt[0];
    for (int idx = blockIdx.x; idx < cnt; idx += gridDim.x) {
        const int g = flaglist[idx];
        const int b = g >> 13;
        __syncthreads();
        xsr[t] = x[(size_t)g * DD + t];
        __syncthreads();
        const float* cbase = centers + (size_t)b * KK * DD;
        double bestv = 1e300; int bestk = 0x7fffffff;
        #pragma unroll
        for (int h = 0; h < 2; ++h) {
            int k = t + h * 256;
            const float* cr = cbase + (size_t)k * DD;
            double a0 = 0, a1 = 0, a2 = 0, a3 = 0;
            for (int d = 0; d < DD; d += 4) {
                float4 cv = *(const float4*)(cr + d);
                double f0 = (double)xsr[d + 0] - (double)cv.x;
                double f1 = (double)xsr[d + 1] - (double)cv.y;
                double f2 = (double)xsr[d + 2] - (double)cv.z;
                double f3 = (double)xsr[d + 3] - (double)cv.w;
                a0 += f0 * f0; a1 += f1 * f1; a2 += f2 * f2; a3 += f3 * f3;
            }
            double dist = (a0 + a1) + (a2 + a3);
            if (dist < bestv || (dist == bestv && k < bestk)) { bestv = dist; bestk = k; }
        }
        sv[t] = bestv; si[t] = bestk;
        __syncthreads();
        for (int s = 128; s > 0; s >>= 1) {
            if (t < s) {
                if (sv[t + s] < sv[t] || (sv[t + s] == sv[t] && si[t + s] < si[t])) {
                    sv[t] = sv[t + s]; si[t] = si[t + s];
                }
            }
            __syncthreads();
        }
        if (t == 0) labels[g] = si[0];
    }
}

// ------- parallel stable counting sort: hist -> scan -> scatter ------------
__global__ __launch_bounds__(64) void chunk_hist_k(const int* __restrict__ labels,
                                                   int* __restrict__ chunkhist) {
    __shared__ int h[KK];
    const int bc = blockIdx.x;        // b*NCH + c
    const int b  = bc >> 7;
    const int c  = bc & (NCH - 1);
    const int t  = threadIdx.x;
    for (int k = t; k < KK; k += 64) h[k] = 0;
    __syncthreads();
    int l = labels[b * NN + c * 64 + t];
    atomicAdd(&h[l], 1);
    __syncthreads();
    int* ch = chunkhist + (size_t)bc * KK;
    for (int k = t; k < KK; k += 64) ch[k] = h[k];
}

__global__ __launch_bounds__(512) void scan_k(int* __restrict__ chunkhist,
                                              int* __restrict__ counts,
                                              int* __restrict__ offsets) {
    __shared__ int s[KK];
    const int b = blockIdx.x;
    const int k = threadIdx.x;
    int* ch = chunkhist + (size_t)b * NCH * KK;
    int run = 0;
    for (int c = 0; c < NCH; ++c) {
        int v = ch[(size_t)c * KK + k];
        ch[(size_t)c * KK + k] = run;
        run += v;
    }
    counts[b * KK + k] = run;
    s[k] = run;
    __syncthreads();
    for (int off = 1; off < KK; off <<= 1) {
        int v = (k >= off) ? s[k - off] : 0;
        __syncthreads();
        s[k] += v;
        __syncthreads();
    }
    offsets[b * KK + k] = s[k] - run;   // exclusive
}

__global__ __launch_bounds__(64) void scatter_k(const int* __restrict__ labels,
                                                const int* __restrict__ chunkhist,
                                                const int* __restrict__ offsets,
                                                int* __restrict__ idxlist) {
    const int bc = blockIdx.x;
    const int b  = bc >> 7;
    const int c  = bc & (NCH - 1);
    const int t  = threadIdx.x;
    const int n  = c * 64 + t;
    const int l  = labels[b * NN + n];
    int rank = 0;
    for (int j = 0; j < 64; ++j) {
        int lj = __shfl(l, j, 64);
        rank += (lj == l && j < t) ? 1 : 0;
    }
    int base = offsets[b * KK + l] + chunkhist[(size_t)bc * KK + l];
    idxlist[b * NN + base + rank] = n;
}

// ------- centers update: member-parallel (16 waves), deterministic ---------
__global__ __launch_bounds__(1024) void centers_update_k(const float* __restrict__ x,
                                                         float* __restrict__ centers,
                                                         f16* __restrict__ ch16,
                                                         const int* __restrict__ counts,
                                                         const int* __restrict__ offsets,
                                                         const int* __restrict__ idxlist,
                                                         int* __restrict__ flagcnt) {
    __shared__ float part[16][DD];
    const int bk   = blockIdx.x;
    const int b    = bk >> 9;
    const int tid  = threadIdx.x;
    const int w    = tid >> 6;        // 0..15
    const int lane = tid & 63;
    if (bk == 0 && tid == 0) flagcnt[0] = 0;   // reset for next assign pass
    const int cnt = counts[bk];
    if (cnt == 0) return;             // uniform across block (f16 mirror stays valid)
    const int* il = idxlist + b * NN + offsets[bk];
    const float* xb = x + (size_t)b * NN * DD;
    float4 acc = {0.f, 0.f, 0.f, 0.f};
    for (int j = w; j < cnt; j += 16) {
        int n = il[j];
        float4 v = *(const float4*)(xb + (size_t)n * DD + lane * 4);
        acc.x = __fadd_rn(acc.x, v.x);
        acc.y = __fadd_rn(acc.y, v.y);
        acc.z = __fadd_rn(acc.z, v.z);
        acc.w = __fadd_rn(acc.w, v.w);
    }
    *(float4*)&part[w][lane * 4] = acc;
    __syncthreads();
    if (tid < DD) {
        float s = 0.f;
        #pragma unroll
        for (int w2 = 0; w2 < 16; ++w2) s = __fadd_rn(s, part[w2][tid]);
        float val = s / (float)cnt;
        centers[(size_t)bk * DD + tid] = val;
        ch16[(size_t)bk * DD + tid] = (f16)val;
    }
}

__global__ __launch_bounds__(256) void labels_to_float_k(const int* __restrict__ labels,
                                                         float* __restrict__ out) {
    int i = blockIdx.x * 256 + threadIdx.x;
    out[i] = (float)labels[i];
}

__global__ __launch_bounds__(256) void copy_centers_k(const float* __restrict__ centers,
                                                      float* __restrict__ out) {
    size_t i = (size_t)blockIdx.x * 256 + threadIdx.x;
    out[i] = centers[i];
}

extern "C" void kernel_launch(void* const* d_in, const int* in_sizes, int n_in,
                              void* d_out, int out_size, void* d_ws, size_t ws_size,
                              hipStream_t stream) {
    const float* x = (const float*)d_in[0];
    float* out = (float*)d_out;
    float* ws  = (float*)d_ws;

    // ws layout
    float* centers  = ws;                                   // BB*KK*DD f32
    float* c2       = centers + (size_t)BB * KK * DD;       // BB*KK
    float* x2       = c2 + BB * KK;                         // BB*NN
    int*   labels   = (int*)(x2 + BB * NN);                 // BB*NN
    int*   flagcnt  = labels + BB * NN;                     // 64
    int*   flaglist = flagcnt + 64;                         // BB*NN
    int*   counts   = flaglist + BB * NN;                   // BB*KK
    int*   offsets  = counts + BB * KK;                     // BB*KK
    int*   idxlist  = offsets + BB * KK;                    // BB*NN
    int*   chunkhist= idxlist + BB * NN;                    // BB*NCH*KK
    f16*   ch16     = (f16*)(chunkhist + (size_t)BB * NCH * KK);  // BB*KK*DD f16

    hipMemsetAsync(flagcnt, 0, 64 * sizeof(int), stream);

    init_centers_k<<<BB * KK, 256, 0, stream>>>(x, centers, ch16);
    rowsumsq_k<<<(BB * NN + 255) / 256, 256, 0, stream>>>(x, x2, BB * NN);

    for (int it = 0; it < NITERS; ++it) {
        rowsumsq_k<<<(BB * KK + 255) / 256, 256, 0, stream>>>(centers, c2, BB * KK);
        assign_k<<<BB * (NN / 64), 256, 0, stream>>>(x, ch16, x2, c2,
                                                     labels, flagcnt, flaglist);
        refine_k<<<1024, 256, 0, stream>>>(x, centers, flagcnt, flaglist, labels);
        chunk_hist_k<<<BB * NCH, 64, 0, stream>>>(labels, chunkhist);
        scan_k<<<BB, 512, 0, stream>>>(chunkhist, counts, offsets);
        scatter_k<<<BB * NCH, 64, 0, stream>>>(labels, chunkhist, offsets, idxlist);
        centers_update_k<<<BB * KK, 1024, 0, stream>>>(x, centers, ch16, counts, offsets,
                                                       idxlist, flagcnt);
    }

    rowsumsq_k<<<(BB * KK + 255) / 256, 256, 0, stream>>>(centers, c2, BB * KK);
    assign_k<<<BB * (NN / 64), 256, 0, stream>>>(x, ch16, x2, c2,
                                                 labels, flagcnt, flaglist);
    refine_k<<<1024, 256, 0, stream>>>(x, centers, flagcnt, flaglist, labels);

    labels_to_float_k<<<BB * NN / 256, 256, 0, stream>>>(labels, out);
    copy_centers_k<<<BB * KK * DD / 256, 256, 0, stream>>>(centers, out + BB * NN);
}